// Round 13
// baseline (234.633 us; speedup 1.0000x reference)
//
#include <hip/hip_runtime.h>
#include <hip/hip_cooperative_groups.h>
#include <math.h>

namespace cg = cooperative_groups;

#define DIM     512
#define NNODES  10000
#define NEDGES  200000
#define MPAD    10048   // 157 * 64
#define NMB     157     // m-groups of 64
#define NGRP    5       // col groups of 2048 (c >> 11)
#define NB      (NGRP * NNODES)   // 50000 buckets
#define SORT_BLK 196              // ceil(NB / 256)

using short8  = __attribute__((ext_vector_type(8))) short;
using floatx4 = __attribute__((ext_vector_type(4))) float;
using half8   = __attribute__((ext_vector_type(8))) _Float16;
using half2v  = __attribute__((ext_vector_type(2))) _Float16;

__device__ inline float dot2acc(half2v a, half2v b, float c) {
#if __has_builtin(__builtin_amdgcn_fdot2)
    return __builtin_amdgcn_fdot2(a, b, c, false);
#else
    return fmaf((float)a[0], (float)b[0], fmaf((float)a[1], (float)b[1], c));
#endif
}

// ---------------------------------------------------------------------------
// prep: (a) Z fp32 -> Zh16 fp16 [MPAD][512] (pad rows zeroed)
//       (b) W fp32 [k][n] -> Wh16t fp16 [n][k] (LDS tile transpose)
// ---------------------------------------------------------------------------
#define PREP_ZBLK 2512
__global__ __launch_bounds__(256) void prep(const float* __restrict__ Z,
                                            const float* __restrict__ W,
                                            _Float16* __restrict__ Zh16,
                                            _Float16* __restrict__ Wh16t) {
    const int b = blockIdx.x;
    const int t = threadIdx.x;

    if (b < PREP_ZBLK) {
        const int idx8 = (b * 256 + t) * 8;
        const int m = idx8 >> 9;
        float x[8];
        if (m < NNODES) {
            float4 v0 = *(const float4*)(Z + idx8);
            float4 v1 = *(const float4*)(Z + idx8 + 4);
            x[0]=v0.x; x[1]=v0.y; x[2]=v0.z; x[3]=v0.w;
            x[4]=v1.x; x[5]=v1.y; x[6]=v1.z; x[7]=v1.w;
        } else {
            #pragma unroll
            for (int j = 0; j < 8; ++j) x[j] = 0.f;
        }
        half8 h;
        #pragma unroll
        for (int j = 0; j < 8; ++j) h[j] = (_Float16)x[j];
        *(half8*)(Zh16 + idx8) = h;
    } else {
        __shared__ float tile[64][65];
        const int wb = b - PREP_ZBLK;      // 0..63
        const int kb = (wb >> 3) * 64;
        const int nb = (wb & 7) * 64;
        const int kk = t >> 2;
        const int ch = t & 3;

        const float* src = W + (size_t)(kb + kk) * DIM + nb + ch * 16;
        #pragma unroll
        for (int q = 0; q < 4; ++q) {
            float4 v = *(const float4*)(src + q * 4);
            tile[kk][ch * 16 + q * 4 + 0] = v.x;
            tile[kk][ch * 16 + q * 4 + 1] = v.y;
            tile[kk][ch * 16 + q * 4 + 2] = v.z;
            tile[kk][ch * 16 + q * 4 + 3] = v.w;
        }
        __syncthreads();

        const int nn = kk;
        half8 h0, h1;
        #pragma unroll
        for (int i = 0; i < 8; ++i) h0[i] = (_Float16)tile[ch * 16 + i][nn];
        #pragma unroll
        for (int i = 0; i < 8; ++i) h1[i] = (_Float16)tile[ch * 16 + 8 + i][nn];
        _Float16* d = Wh16t + (size_t)(nb + nn) * DIM + kb + ch * 16;
        *(half8*)(d)     = h0;
        *(half8*)(d + 8) = h1;
    }
}

// ---------------------------------------------------------------------------
// GEMM: single-pass fp16 MFMA.  64m x 128n block, BK=32, 16 steps, grid 628.
// A/B via global_load_lds into double-buffered LDS, ONE barrier per step.
// ---------------------------------------------------------------------------
__global__ __launch_bounds__(256) void gemm_f16(const _Float16* __restrict__ Zh16,
                                                const _Float16* __restrict__ Wh16t,
                                                _Float16* __restrict__ ZWh) {
    __shared__ _Float16 Abuf[2][64 * 32];
    __shared__ _Float16 Bbuf[2][128 * 32];

    const int t     = threadIdx.x;
    const int bid   = blockIdx.x;
    const int n_idx = bid & 3;
    const int m0    = (bid >> 2) * 64;
    const int n0    = n_idx * 128;

    const int l  = t & 63;
    const int w  = t >> 6;
    const int wn = w * 32;
    const int lm = l & 15;
    const int lq = l >> 4;
    const unsigned wbase = (unsigned)(t & 192);

    floatx4 acc[4][2] = {};

    const int arow = t >> 2;
    const int ach  = t & 3;

    auto stage = [&](int buf, int k0) {
        {
            const _Float16* s = Zh16 + (size_t)(m0 + arow) * DIM + k0 + ach * 8;
            __builtin_amdgcn_global_load_lds(
                (const __attribute__((address_space(1))) void*)s,
                (__attribute__((address_space(3))) void*)&Abuf[buf][wbase * 8], 16, 0, 0);
        }
        #pragma unroll
        for (int p = 0; p < 2; ++p) {
            const int sidx = p * 256 + t;
            const int row  = sidx >> 2;
            const int ch   = sidx & 3;
            const _Float16* s = Wh16t + (size_t)(n0 + row) * DIM + k0 + ch * 8;
            __builtin_amdgcn_global_load_lds(
                (const __attribute__((address_space(1))) void*)s,
                (__attribute__((address_space(3))) void*)&Bbuf[buf][(p * 256 + wbase) * 8], 16, 0, 0);
        }
    };

    stage(0, 0);
    __syncthreads();

    for (int s = 0; s < 16; ++s) {
        const int buf = s & 1;
        if (s < 15) stage(buf ^ 1, (s + 1) * 32);

        half8 aF[4], bF[2];
        #pragma unroll
        for (int i = 0; i < 4; ++i)
            aF[i] = *(const half8*)&Abuf[buf][(16 * i + lm) * 32 + lq * 8];
        #pragma unroll
        for (int j = 0; j < 2; ++j)
            bF[j] = *(const half8*)&Bbuf[buf][(wn + 16 * j + lm) * 32 + lq * 8];

        #pragma unroll
        for (int i = 0; i < 4; ++i)
            #pragma unroll
            for (int j = 0; j < 2; ++j)
                acc[i][j] = __builtin_amdgcn_mfma_f32_16x16x32_f16(aF[i], bF[j], acc[i][j], 0, 0, 0);

        __syncthreads();
    }

    #pragma unroll
    for (int i = 0; i < 4; ++i)
        #pragma unroll
        for (int j = 0; j < 2; ++j)
            #pragma unroll
            for (int r = 0; r < 4; ++r) {
                const int gm = m0 + 16 * i + lq * 4 + r;
                const int gn = n0 + wn + 16 * j + lm;
                if (gm < NNODES)
                    ZWh[(size_t)gm * DIM + gn] = (_Float16)acc[i][j][r];
            }
}

// ---------------------------------------------------------------------------
// Fused cooperative sort: zero -> hist -> scan(block) -> scan(fix) -> scatter
// bucket = (c>>11)*NNODES + r.  Grid: 196 blocks x 256 threads (co-resident).
// ---------------------------------------------------------------------------
__global__ __launch_bounds__(256) void sort_all(const int* __restrict__ eidx,
                                                int* __restrict__ counts,
                                                int* __restrict__ partial,
                                                int* __restrict__ blksum,
                                                int* __restrict__ offs,
                                                int* __restrict__ cursor,
                                                unsigned* __restrict__ keys) {
    cg::grid_group grid = cg::this_grid();
    const int b = blockIdx.x;
    const int t = threadIdx.x;
    const int gt = b * 256 + t;
    const int nthreads = SORT_BLK * 256;

    // phase 0: zero counts
    if (gt < NB) counts[gt] = 0;
    grid.sync();

    // phase 1: histogram
    for (int e = gt; e < NEDGES; e += nthreads) {
        int r = eidx[e];
        int c = eidx[NEDGES + e];
        atomicAdd(&counts[(c >> 11) * NNODES + r], 1);
    }
    grid.sync();

    // phase 2: per-block exclusive scan of 256 contiguous counters
    {
        __shared__ int wsum[4];
        __shared__ int woff[5];
        const int lane = t & 63;
        const int wv   = t >> 6;

        int x = (gt < NB) ? counts[gt] : 0;
        int v = x;
        #pragma unroll
        for (int off = 1; off < 64; off <<= 1) {
            int u = __shfl_up(v, off, 64);
            if (lane >= off) v += u;
        }
        if (lane == 63) wsum[wv] = v;
        __syncthreads();
        if (t == 0) {
            int r = 0;
            #pragma unroll
            for (int k = 0; k < 4; ++k) { woff[k] = r; r += wsum[k]; }
            woff[4] = r;
        }
        __syncthreads();
        if (gt < NB) partial[gt] = woff[wv] + (v - x);
        if (t == 255) blksum[b] = woff[4];
    }
    grid.sync();

    // phase 3: add block base, emit offs/cursor
    {
        __shared__ int psum[4];
        __shared__ int base_s;
        const int lane = t & 63;
        const int wv   = t >> 6;
        int v = (t < b) ? blksum[t] : 0;     // b <= 195 < 256
        #pragma unroll
        for (int off = 32; off > 0; off >>= 1)
            v += __shfl_xor(v, off, 64);
        if (lane == 0) psum[wv] = v;
        __syncthreads();
        if (t == 0) base_s = psum[0] + psum[1] + psum[2] + psum[3];
        __syncthreads();
        const int base = base_s;
        if (gt < NB) {
            int off = base + partial[gt];
            offs[gt]   = off;
            cursor[gt] = off;
            if (gt == NB - 1) offs[NB] = off + counts[gt];
        }
    }
    grid.sync();

    // phase 4: scatter
    for (int e = gt; e < NEDGES; e += nthreads) {
        int r = eidx[e];
        int c = eidx[NEDGES + e];
        int pos = atomicAdd(&cursor[(c >> 11) * NNODES + r], 1);
        keys[pos] = ((unsigned)c << 18) | (unsigned)e;
    }
}

// ---------------------------------------------------------------------------
// Non-cooperative fallback pieces (used if cooperative launch fails)
// ---------------------------------------------------------------------------
__global__ void zero_counts_k(int* __restrict__ counts) {
    int i = blockIdx.x * blockDim.x + threadIdx.x;
    if (i < NB) counts[i] = 0;
}

__global__ void hist_rows(const int* __restrict__ eidx, int* __restrict__ counts) {
    int e = blockIdx.x * blockDim.x + threadIdx.x;
    if (e < NEDGES) {
        int r = eidx[e];
        int c = eidx[NEDGES + e];
        atomicAdd(&counts[(c >> 11) * NNODES + r], 1);
    }
}

__global__ __launch_bounds__(1024) void scan_local(const int* __restrict__ counts,
                                                   int* __restrict__ partial,
                                                   int* __restrict__ blksum) {
    __shared__ int wsum[16];
    __shared__ int woff[17];
    const int t    = threadIdx.x;
    const int lane = t & 63;
    const int wv   = t >> 6;
    const int i    = blockIdx.x * 1024 + t;

    int x = (i < NB) ? counts[i] : 0;

    int v = x;
    #pragma unroll
    for (int off = 1; off < 64; off <<= 1) {
        int u = __shfl_up(v, off, 64);
        if (lane >= off) v += u;
    }
    if (lane == 63) wsum[wv] = v;
    __syncthreads();
    if (t == 0) {
        int r = 0;
        #pragma unroll
        for (int k = 0; k < 16; ++k) { woff[k] = r; r += wsum[k]; }
        woff[16] = r;
    }
    __syncthreads();

    if (i < NB) partial[i] = woff[wv] + (v - x);
    if (t == 1023) blksum[blockIdx.x] = woff[16];
}

__global__ __launch_bounds__(1024) void scan_fix(const int* __restrict__ counts,
                                                 const int* __restrict__ partial,
                                                 const int* __restrict__ blksum,
                                                 int* __restrict__ offs,
                                                 int* __restrict__ cursor) {
    __shared__ int base_s;
    const int t = threadIdx.x;
    const int b = blockIdx.x;

    if (t < 64) {
        int v = (t < b) ? blksum[t] : 0;     // 49 blocks <= 64
        #pragma unroll
        for (int off = 32; off > 0; off >>= 1)
            v += __shfl_xor(v, off, 64);
        if (t == 0) base_s = v;
    }
    __syncthreads();
    const int base = base_s;

    const int i = b * 1024 + t;
    if (i < NB) {
        int off = base + partial[i];
        offs[i]   = off;
        cursor[i] = off;
        if (i == NB - 1) offs[NB] = off + counts[i];
    }
}

__global__ void scatter_edges(const int* __restrict__ eidx,
                              int* __restrict__ cursor,
                              unsigned* __restrict__ keys) {
    int e = blockIdx.x * blockDim.x + threadIdx.x;
    if (e < NEDGES) {
        int r = eidx[e];
        int c = eidx[NEDGES + e];
        int pos = atomicAdd(&cursor[(c >> 11) * NNODES + r], 1);
        keys[pos] = ((unsigned)c << 18) | (unsigned)e;
    }
}

// ---------------------------------------------------------------------------
// Edge scoring: one wave per (col-group, row) bucket; 16 lanes/edge,
// 4 edges/wave in parallel; gathers confined to one 2 MB slice at a time.
// ---------------------------------------------------------------------------
__global__ __launch_bounds__(256) void edge_score_q(const _Float16* __restrict__ ZWh,
                                                    const _Float16* __restrict__ Zh,
                                                    const unsigned* __restrict__ keys,
                                                    const int* __restrict__ offs,
                                                    float* __restrict__ out) {
    const int b = blockIdx.x * 4 + (threadIdx.x >> 6);
    const int start = offs[b];
    const int end   = offs[b + 1];
    if (start == end) return;

    const unsigned g = (unsigned)b / NNODES;
    const int r = b - (int)g * NNODES;

    const int lane = threadIdx.x & 63;
    const int gq   = lane >> 4;
    const int sl   = lane & 15;

    const _Float16* rp = ZWh + (size_t)r * DIM + sl * 32;
    half8 ra0 = *(const half8*)(rp);
    half8 ra1 = *(const half8*)(rp + 8);
    half8 ra2 = *(const half8*)(rp + 16);
    half8 ra3 = *(const half8*)(rp + 24);

    for (int i = start; i < end; i += 4) {
        const int ii = i + gq;
        const unsigned k = keys[ii < end ? ii : (end - 1)];
        const int c = (int)(k >> 18);

        const _Float16* cp = Zh + (size_t)c * DIM + sl * 32;
        half8 c0 = *(const half8*)(cp);
        half8 c1 = *(const half8*)(cp + 8);
        half8 c2 = *(const half8*)(cp + 16);
        half8 c3 = *(const half8*)(cp + 24);

        float s = 0.f;
        #pragma unroll
        for (int d = 0; d < 4; ++d) {
            s = dot2acc((half2v){ra0[2*d], ra0[2*d+1]}, (half2v){c0[2*d], c0[2*d+1]}, s);
            s = dot2acc((half2v){ra1[2*d], ra1[2*d+1]}, (half2v){c1[2*d], c1[2*d+1]}, s);
            s = dot2acc((half2v){ra2[2*d], ra2[2*d+1]}, (half2v){c2[2*d], c2[2*d+1]}, s);
            s = dot2acc((half2v){ra3[2*d], ra3[2*d+1]}, (half2v){c3[2*d], c3[2*d+1]}, s);
        }

        s += __shfl_xor(s, 1, 64);
        s += __shfl_xor(s, 2, 64);
        s += __shfl_xor(s, 4, 64);
        s += __shfl_xor(s, 8, 64);

        if (sl == 0 && ii < end)
            out[k & 0x3FFFFu] = 1.0f / (1.0f + expf(-s));
    }
}

// ---------------------------------------------------------------------------
// fp32 fallback path (ws too small)
// ---------------------------------------------------------------------------
#define GTM 128
#define GTN 64
#define GTK 16
#define LDA 132
#define LDB 68

__global__ __launch_bounds__(256) void gemm_zw(const float* __restrict__ A,
                                               const float* __restrict__ B,
                                               float* __restrict__ C) {
    __shared__ float As[GTK * LDA];
    __shared__ float Bs[GTK * LDB];

    const int t  = threadIdx.x;
    const int m0 = blockIdx.x * GTM;
    const int n0 = blockIdx.y * GTN;
    const int tx = t & 15;
    const int ty = t >> 4;

    float acc[8][4] = {};

    for (int k0 = 0; k0 < DIM; k0 += GTK) {
        #pragma unroll
        for (int p = 0; p < 2; ++p) {
            int f  = t + p * 256;
            int mm = f >> 2;
            int kq = f & 3;
            int m  = m0 + mm;
            float4 v = make_float4(0.f, 0.f, 0.f, 0.f);
            if (m < NNODES)
                v = *(const float4*)(A + (size_t)m * DIM + k0 + kq * 4);
            As[(kq * 4 + 0) * LDA + mm] = v.x;
            As[(kq * 4 + 1) * LDA + mm] = v.y;
            As[(kq * 4 + 2) * LDA + mm] = v.z;
            As[(kq * 4 + 3) * LDA + mm] = v.w;
        }
        {
            int kb = t >> 4, n4 = t & 15;
            *(float4*)&Bs[kb * LDB + n4 * 4] =
                *(const float4*)(B + (size_t)(k0 + kb) * DIM + n0 + n4 * 4);
        }
        __syncthreads();

        #pragma unroll
        for (int kk = 0; kk < GTK; ++kk) {
            float4 a0 = *(const float4*)&As[kk * LDA + ty * 8];
            float4 a1 = *(const float4*)&As[kk * LDA + ty * 8 + 4];
            float4 b  = *(const float4*)&Bs[kk * LDB + tx * 4];
            float av[8] = {a0.x, a0.y, a0.z, a0.w, a1.x, a1.y, a1.z, a1.w};
            float bv[4] = {b.x, b.y, b.z, b.w};
            #pragma unroll
            for (int i = 0; i < 8; ++i)
                #pragma unroll
                for (int j = 0; j < 4; ++j)
                    acc[i][j] = fmaf(av[i], bv[j], acc[i][j]);
        }
        __syncthreads();
    }

    #pragma unroll
    for (int i = 0; i < 8; ++i) {
        int m = m0 + ty * 8 + i;
        if (m < NNODES)
            *(float4*)(C + (size_t)m * DIM + n0 + tx * 4) =
                make_float4(acc[i][0], acc[i][1], acc[i][2], acc[i][3]);
    }
}

__global__ __launch_bounds__(256) void edge_score(const float* __restrict__ ZW,
                                                  const float* __restrict__ Z,
                                                  const int* __restrict__ eidx,
                                                  float* __restrict__ out) {
    const int e    = blockIdx.x * 4 + (threadIdx.x >> 6);
    const int lane = threadIdx.x & 63;

    const int r = eidx[e];
    const int c = eidx[NEDGES + e];

    const float4* pr = (const float4*)(ZW + (size_t)r * DIM);
    const float4* pc = (const float4*)(Z  + (size_t)c * DIM);

    float4 a0 = pr[lane * 2 + 0];
    float4 a1 = pr[lane * 2 + 1];
    float4 b0 = pc[lane * 2 + 0];
    float4 b1 = pc[lane * 2 + 1];

    float s = a0.x * b0.x;
    s = fmaf(a0.y, b0.y, s);
    s = fmaf(a0.z, b0.z, s);
    s = fmaf(a0.w, b0.w, s);
    s = fmaf(a1.x, b1.x, s);
    s = fmaf(a1.y, b1.y, s);
    s = fmaf(a1.z, b1.z, s);
    s = fmaf(a1.w, b1.w, s);

    #pragma unroll
    for (int off = 32; off > 0; off >>= 1)
        s += __shfl_xor(s, off, 64);

    if (lane == 0)
        out[e] = 1.0f / (1.0f + expf(-s));
}

// ---------------------------------------------------------------------------
extern "C" void kernel_launch(void* const* d_in, const int* in_sizes, int n_in,
                              void* d_out, int out_size, void* d_ws, size_t ws_size,
                              hipStream_t stream) {
    const float* Z  = (const float*)d_in[0];
    const float* W  = (const float*)d_in[1];
    const int*   EI = (const int*)d_in[2];
    float* out = (float*)d_out;

    char* p = (char*)d_ws;
    _Float16* ZWh   = (_Float16*)p;  p += (size_t)MPAD * DIM * 2;
    _Float16* Zh16  = (_Float16*)p;  p += (size_t)MPAD * DIM * 2;
    _Float16* Wh16t = (_Float16*)p;  p += (size_t)DIM * DIM * 2;
    int* counts  = (int*)p;          p += (size_t)NB * 4;
    int* offs    = (int*)p;          p += (size_t)(NB + 1) * 4;
    int* cursor  = (int*)p;          p += (size_t)NB * 4;
    int* partial = (int*)p;          p += (size_t)NB * 4;
    int* blksum  = (int*)p;          p += (size_t)SORT_BLK * 4;
    unsigned* keys = (unsigned*)p;   p += (size_t)NEDGES * 4;
    const size_t need_full = (size_t)(p - (char*)d_ws);

    if (ws_size >= need_full) {
        prep<<<PREP_ZBLK + 64, 256, 0, stream>>>(Z, W, Zh16, Wh16t);
        gemm_f16<<<NMB * 4, 256, 0, stream>>>(Zh16, Wh16t, ZWh);

        // fused cooperative sort; fall back to 5-kernel chain if launch fails
        void* args[] = {(void*)&EI, (void*)&counts, (void*)&partial,
                        (void*)&blksum, (void*)&offs, (void*)&cursor, (void*)&keys};
        hipError_t err = hipLaunchCooperativeKernel(
            reinterpret_cast<void*>(sort_all), dim3(SORT_BLK), dim3(256),
            args, 0, stream);
        if (err != hipSuccess) {
            zero_counts_k<<<(NB + 255) / 256, 256, 0, stream>>>(counts);
            hist_rows<<<(NEDGES + 255) / 256, 256, 0, stream>>>(EI, counts);
            scan_local<<<49, 1024, 0, stream>>>(counts, partial, blksum);
            scan_fix<<<49, 1024, 0, stream>>>(counts, partial, blksum, offs, cursor);
            scatter_edges<<<(NEDGES + 255) / 256, 256, 0, stream>>>(EI, cursor, keys);
        }

        edge_score_q<<<NB / 4, 256, 0, stream>>>(ZWh, Zh16, keys, offs, out);
    } else {
        float* ZW = (float*)d_ws;
        dim3 g1((NNODES + GTM - 1) / GTM, DIM / GTN);
        gemm_zw<<<g1, 256, 0, stream>>>(Z, W, ZW);
        edge_score<<<NEDGES / 4, 256, 0, stream>>>(ZW, Z, EI, out);
    }
}

// Round 14
// 143.762 us; speedup vs baseline: 1.6321x; 1.6321x over previous
//
#include <hip/hip_runtime.h>
#include <math.h>

#define DIM     512
#define NNODES  10000
#define NEDGES  200000
#define MPAD    10048   // 157 * 64
#define NMB     157     // m-groups of 64
#define NGRP    5       // col groups of 2048 (c >> 11)
#define NB      (NGRP * NNODES)   // 50000 buckets
#define SCAN_BLK 49               // ceil(NB / 1024)

using short8  = __attribute__((ext_vector_type(8))) short;
using floatx4 = __attribute__((ext_vector_type(4))) float;
using half8   = __attribute__((ext_vector_type(8))) _Float16;
using half2v  = __attribute__((ext_vector_type(2))) _Float16;

__device__ inline float dot2acc(half2v a, half2v b, float c) {
#if __has_builtin(__builtin_amdgcn_fdot2)
    return __builtin_amdgcn_fdot2(a, b, c, false);
#else
    return fmaf((float)a[0], (float)b[0], fmaf((float)a[1], (float)b[1], c));
#endif
}

// ---------------------------------------------------------------------------
// prep: fused  (a) Z fp32 -> Zh16 fp16 [MPAD][512] (pad rows zeroed)
//              (b) W fp32 [k][n] -> Wh16t fp16 [n][k] (LDS tile transpose)
//              (c) zero bucket counts (50k)
// ---------------------------------------------------------------------------
#define PREP_ZBLK 2512
__global__ __launch_bounds__(256) void prep(const float* __restrict__ Z,
                                            const float* __restrict__ W,
                                            _Float16* __restrict__ Zh16,
                                            _Float16* __restrict__ Wh16t,
                                            int* __restrict__ counts) {
    const int b = blockIdx.x;
    const int t = threadIdx.x;

    if (b < 196) {                      // 196*256 = 50176 >= NB
        int i = b * 256 + t;
        if (i < NB) counts[i] = 0;
    }

    if (b < PREP_ZBLK) {
        const int idx8 = (b * 256 + t) * 8;
        const int m = idx8 >> 9;
        float x[8];
        if (m < NNODES) {
            float4 v0 = *(const float4*)(Z + idx8);
            float4 v1 = *(const float4*)(Z + idx8 + 4);
            x[0]=v0.x; x[1]=v0.y; x[2]=v0.z; x[3]=v0.w;
            x[4]=v1.x; x[5]=v1.y; x[6]=v1.z; x[7]=v1.w;
        } else {
            #pragma unroll
            for (int j = 0; j < 8; ++j) x[j] = 0.f;
        }
        half8 h;
        #pragma unroll
        for (int j = 0; j < 8; ++j) h[j] = (_Float16)x[j];
        *(half8*)(Zh16 + idx8) = h;
    } else {
        __shared__ float tile[64][65];
        const int wb = b - PREP_ZBLK;      // 0..63
        const int kb = (wb >> 3) * 64;
        const int nb = (wb & 7) * 64;
        const int kk = t >> 2;
        const int ch = t & 3;

        const float* src = W + (size_t)(kb + kk) * DIM + nb + ch * 16;
        #pragma unroll
        for (int q = 0; q < 4; ++q) {
            float4 v = *(const float4*)(src + q * 4);
            tile[kk][ch * 16 + q * 4 + 0] = v.x;
            tile[kk][ch * 16 + q * 4 + 1] = v.y;
            tile[kk][ch * 16 + q * 4 + 2] = v.z;
            tile[kk][ch * 16 + q * 4 + 3] = v.w;
        }
        __syncthreads();

        const int nn = kk;
        half8 h0, h1;
        #pragma unroll
        for (int i = 0; i < 8; ++i) h0[i] = (_Float16)tile[ch * 16 + i][nn];
        #pragma unroll
        for (int i = 0; i < 8; ++i) h1[i] = (_Float16)tile[ch * 16 + 8 + i][nn];
        _Float16* d = Wh16t + (size_t)(nb + nn) * DIM + kb + ch * 16;
        *(half8*)(d)     = h0;
        *(half8*)(d + 8) = h1;
    }
}

// ---------------------------------------------------------------------------
// GEMM: single-pass fp16 MFMA.  64m x 128n block, BK=32, 16 steps, grid 628.
// A/B via global_load_lds into double-buffered LDS, ONE barrier per step.
// ---------------------------------------------------------------------------
__global__ __launch_bounds__(256) void gemm_f16(const _Float16* __restrict__ Zh16,
                                                const _Float16* __restrict__ Wh16t,
                                                _Float16* __restrict__ ZWh) {
    __shared__ _Float16 Abuf[2][64 * 32];
    __shared__ _Float16 Bbuf[2][128 * 32];

    const int t     = threadIdx.x;
    const int bid   = blockIdx.x;
    const int n_idx = bid & 3;
    const int m0    = (bid >> 2) * 64;
    const int n0    = n_idx * 128;

    const int l  = t & 63;
    const int w  = t >> 6;
    const int wn = w * 32;
    const int lm = l & 15;
    const int lq = l >> 4;
    const unsigned wbase = (unsigned)(t & 192);

    floatx4 acc[4][2] = {};

    const int arow = t >> 2;
    const int ach  = t & 3;

    auto stage = [&](int buf, int k0) {
        {
            const _Float16* s = Zh16 + (size_t)(m0 + arow) * DIM + k0 + ach * 8;
            __builtin_amdgcn_global_load_lds(
                (const __attribute__((address_space(1))) void*)s,
                (__attribute__((address_space(3))) void*)&Abuf[buf][wbase * 8], 16, 0, 0);
        }
        #pragma unroll
        for (int p = 0; p < 2; ++p) {
            const int sidx = p * 256 + t;
            const int row  = sidx >> 2;
            const int ch   = sidx & 3;
            const _Float16* s = Wh16t + (size_t)(n0 + row) * DIM + k0 + ch * 8;
            __builtin_amdgcn_global_load_lds(
                (const __attribute__((address_space(1))) void*)s,
                (__attribute__((address_space(3))) void*)&Bbuf[buf][(p * 256 + wbase) * 8], 16, 0, 0);
        }
    };

    stage(0, 0);
    __syncthreads();

    for (int s = 0; s < 16; ++s) {
        const int buf = s & 1;
        if (s < 15) stage(buf ^ 1, (s + 1) * 32);

        half8 aF[4], bF[2];
        #pragma unroll
        for (int i = 0; i < 4; ++i)
            aF[i] = *(const half8*)&Abuf[buf][(16 * i + lm) * 32 + lq * 8];
        #pragma unroll
        for (int j = 0; j < 2; ++j)
            bF[j] = *(const half8*)&Bbuf[buf][(wn + 16 * j + lm) * 32 + lq * 8];

        #pragma unroll
        for (int i = 0; i < 4; ++i)
            #pragma unroll
            for (int j = 0; j < 2; ++j)
                acc[i][j] = __builtin_amdgcn_mfma_f32_16x16x32_f16(aF[i], bF[j], acc[i][j], 0, 0, 0);

        __syncthreads();
    }

    #pragma unroll
    for (int i = 0; i < 4; ++i)
        #pragma unroll
        for (int j = 0; j < 2; ++j)
            #pragma unroll
            for (int r = 0; r < 4; ++r) {
                const int gm = m0 + 16 * i + lq * 4 + r;
                const int gn = n0 + wn + 16 * j + lm;
                if (gm < NNODES)
                    ZWh[(size_t)gm * DIM + gn] = (_Float16)acc[i][j][r];
            }
}

// ---------------------------------------------------------------------------
// Counting sort by (col-group, row): bucket = (c>>11)*NNODES + r
// ---------------------------------------------------------------------------
__global__ void hist_rows(const int* __restrict__ eidx, int* __restrict__ counts) {
    int e = blockIdx.x * blockDim.x + threadIdx.x;
    if (e < NEDGES) {
        int r = eidx[e];
        int c = eidx[NEDGES + e];
        atomicAdd(&counts[(c >> 11) * NNODES + r], 1);
    }
}

// Phase 1: per-block exclusive scan (1024 contiguous counters per block).
__global__ __launch_bounds__(1024) void scan_local(const int* __restrict__ counts,
                                                   int* __restrict__ partial,
                                                   int* __restrict__ blksum) {
    __shared__ int wsum[16];
    __shared__ int woff[17];
    const int t    = threadIdx.x;
    const int lane = t & 63;
    const int wv   = t >> 6;
    const int i    = blockIdx.x * 1024 + t;

    int x = (i < NB) ? counts[i] : 0;

    int v = x;   // inclusive wave scan
    #pragma unroll
    for (int off = 1; off < 64; off <<= 1) {
        int u = __shfl_up(v, off, 64);
        if (lane >= off) v += u;
    }
    if (lane == 63) wsum[wv] = v;
    __syncthreads();
    if (t == 0) {
        int r = 0;
        #pragma unroll
        for (int k = 0; k < 16; ++k) { woff[k] = r; r += wsum[k]; }
        woff[16] = r;
    }
    __syncthreads();

    if (i < NB) partial[i] = woff[wv] + (v - x);   // block-local exclusive
    if (t == 1023) blksum[blockIdx.x] = woff[16];
}

// Phase 2: add block-base (wave-reduction over blksum) and emit offs/cursor.
__global__ __launch_bounds__(1024) void scan_fix(const int* __restrict__ counts,
                                                 const int* __restrict__ partial,
                                                 const int* __restrict__ blksum,
                                                 int* __restrict__ offs,
                                                 int* __restrict__ cursor) {
    __shared__ int base_s;
    const int t = threadIdx.x;
    const int b = blockIdx.x;

    if (t < 64) {
        int v = (t < b) ? blksum[t] : 0;     // SCAN_BLK=49 <= 64
        #pragma unroll
        for (int off = 32; off > 0; off >>= 1)
            v += __shfl_xor(v, off, 64);
        if (t == 0) base_s = v;
    }
    __syncthreads();
    const int base = base_s;

    const int i = b * 1024 + t;
    if (i < NB) {
        int off = base + partial[i];
        offs[i]   = off;
        cursor[i] = off;
        if (i == NB - 1) offs[NB] = off + counts[i];
    }
}

__global__ void scatter_edges(const int* __restrict__ eidx,
                              int* __restrict__ cursor,
                              unsigned* __restrict__ keys) {
    int e = blockIdx.x * blockDim.x + threadIdx.x;
    if (e < NEDGES) {
        int r = eidx[e];
        int c = eidx[NEDGES + e];
        int pos = atomicAdd(&cursor[(c >> 11) * NNODES + r], 1);
        keys[pos] = ((unsigned)c << 18) | (unsigned)e;
    }
}

// ---------------------------------------------------------------------------
// Edge scoring: one wave per (col-group, row) bucket; 16 lanes/edge,
// 4 edges/wave in parallel; gathers confined to one 2 MB slice at a time.
// ---------------------------------------------------------------------------
__global__ __launch_bounds__(256) void edge_score_q(const _Float16* __restrict__ ZWh,
                                                    const _Float16* __restrict__ Zh,
                                                    const unsigned* __restrict__ keys,
                                                    const int* __restrict__ offs,
                                                    float* __restrict__ out) {
    const int b = blockIdx.x * 4 + (threadIdx.x >> 6);
    const int start = offs[b];
    const int end   = offs[b + 1];
    if (start == end) return;

    const unsigned g = (unsigned)b / NNODES;
    const int r = b - (int)g * NNODES;

    const int lane = threadIdx.x & 63;
    const int gq   = lane >> 4;
    const int sl   = lane & 15;

    const _Float16* rp = ZWh + (size_t)r * DIM + sl * 32;
    half8 ra0 = *(const half8*)(rp);
    half8 ra1 = *(const half8*)(rp + 8);
    half8 ra2 = *(const half8*)(rp + 16);
    half8 ra3 = *(const half8*)(rp + 24);

    for (int i = start; i < end; i += 4) {
        const int ii = i + gq;
        const unsigned k = keys[ii < end ? ii : (end - 1)];
        const int c = (int)(k >> 18);

        const _Float16* cp = Zh + (size_t)c * DIM + sl * 32;
        half8 c0 = *(const half8*)(cp);
        half8 c1 = *(const half8*)(cp + 8);
        half8 c2 = *(const half8*)(cp + 16);
        half8 c3 = *(const half8*)(cp + 24);

        float s = 0.f;
        #pragma unroll
        for (int d = 0; d < 4; ++d) {
            s = dot2acc((half2v){ra0[2*d], ra0[2*d+1]}, (half2v){c0[2*d], c0[2*d+1]}, s);
            s = dot2acc((half2v){ra1[2*d], ra1[2*d+1]}, (half2v){c1[2*d], c1[2*d+1]}, s);
            s = dot2acc((half2v){ra2[2*d], ra2[2*d+1]}, (half2v){c2[2*d], c2[2*d+1]}, s);
            s = dot2acc((half2v){ra3[2*d], ra3[2*d+1]}, (half2v){c3[2*d], c3[2*d+1]}, s);
        }

        s += __shfl_xor(s, 1, 64);
        s += __shfl_xor(s, 2, 64);
        s += __shfl_xor(s, 4, 64);
        s += __shfl_xor(s, 8, 64);

        if (sl == 0 && ii < end)
            out[k & 0x3FFFFu] = 1.0f / (1.0f + expf(-s));
    }
}

// ---------------------------------------------------------------------------
// fp32 fallback path (ws too small)
// ---------------------------------------------------------------------------
#define GTM 128
#define GTN 64
#define GTK 16
#define LDA 132
#define LDB 68

__global__ __launch_bounds__(256) void gemm_zw(const float* __restrict__ A,
                                               const float* __restrict__ B,
                                               float* __restrict__ C) {
    __shared__ float As[GTK * LDA];
    __shared__ float Bs[GTK * LDB];

    const int t  = threadIdx.x;
    const int m0 = blockIdx.x * GTM;
    const int n0 = blockIdx.y * GTN;
    const int tx = t & 15;
    const int ty = t >> 4;

    float acc[8][4] = {};

    for (int k0 = 0; k0 < DIM; k0 += GTK) {
        #pragma unroll
        for (int p = 0; p < 2; ++p) {
            int f  = t + p * 256;
            int mm = f >> 2;
            int kq = f & 3;
            int m  = m0 + mm;
            float4 v = make_float4(0.f, 0.f, 0.f, 0.f);
            if (m < NNODES)
                v = *(const float4*)(A + (size_t)m * DIM + k0 + kq * 4);
            As[(kq * 4 + 0) * LDA + mm] = v.x;
            As[(kq * 4 + 1) * LDA + mm] = v.y;
            As[(kq * 4 + 2) * LDA + mm] = v.z;
            As[(kq * 4 + 3) * LDA + mm] = v.w;
        }
        {
            int kb = t >> 4, n4 = t & 15;
            *(float4*)&Bs[kb * LDB + n4 * 4] =
                *(const float4*)(B + (size_t)(k0 + kb) * DIM + n0 + n4 * 4);
        }
        __syncthreads();

        #pragma unroll
        for (int kk = 0; kk < GTK; ++kk) {
            float4 a0 = *(const float4*)&As[kk * LDA + ty * 8];
            float4 a1 = *(const float4*)&As[kk * LDA + ty * 8 + 4];
            float4 b  = *(const float4*)&Bs[kk * LDB + tx * 4];
            float av[8] = {a0.x, a0.y, a0.z, a0.w, a1.x, a1.y, a1.z, a1.w};
            float bv[4] = {b.x, b.y, b.z, b.w};
            #pragma unroll
            for (int i = 0; i < 8; ++i)
                #pragma unroll
                for (int j = 0; j < 4; ++j)
                    acc[i][j] = fmaf(av[i], bv[j], acc[i][j]);
        }
        __syncthreads();
    }

    #pragma unroll
    for (int i = 0; i < 8; ++i) {
        int m = m0 + ty * 8 + i;
        if (m < NNODES)
            *(float4*)(C + (size_t)m * DIM + n0 + tx * 4) =
                make_float4(acc[i][0], acc[i][1], acc[i][2], acc[i][3]);
    }
}

__global__ __launch_bounds__(256) void edge_score(const float* __restrict__ ZW,
                                                  const float* __restrict__ Z,
                                                  const int* __restrict__ eidx,
                                                  float* __restrict__ out) {
    const int e    = blockIdx.x * 4 + (threadIdx.x >> 6);
    const int lane = threadIdx.x & 63;

    const int r = eidx[e];
    const int c = eidx[NEDGES + e];

    const float4* pr = (const float4*)(ZW + (size_t)r * DIM);
    const float4* pc = (const float4*)(Z  + (size_t)c * DIM);

    float4 a0 = pr[lane * 2 + 0];
    float4 a1 = pr[lane * 2 + 1];
    float4 b0 = pc[lane * 2 + 0];
    float4 b1 = pc[lane * 2 + 1];

    float s = a0.x * b0.x;
    s = fmaf(a0.y, b0.y, s);
    s = fmaf(a0.z, b0.z, s);
    s = fmaf(a0.w, b0.w, s);
    s = fmaf(a1.x, b1.x, s);
    s = fmaf(a1.y, b1.y, s);
    s = fmaf(a1.z, b1.z, s);
    s = fmaf(a1.w, b1.w, s);

    #pragma unroll
    for (int off = 32; off > 0; off >>= 1)
        s += __shfl_xor(s, off, 64);

    if (lane == 0)
        out[e] = 1.0f / (1.0f + expf(-s));
}

// ---------------------------------------------------------------------------
extern "C" void kernel_launch(void* const* d_in, const int* in_sizes, int n_in,
                              void* d_out, int out_size, void* d_ws, size_t ws_size,
                              hipStream_t stream) {
    const float* Z  = (const float*)d_in[0];
    const float* W  = (const float*)d_in[1];
    const int*   EI = (const int*)d_in[2];
    float* out = (float*)d_out;

    char* p = (char*)d_ws;
    _Float16* ZWh   = (_Float16*)p;  p += (size_t)MPAD * DIM * 2;
    _Float16* Zh16  = (_Float16*)p;  p += (size_t)MPAD * DIM * 2;
    _Float16* Wh16t = (_Float16*)p;  p += (size_t)DIM * DIM * 2;
    int* counts  = (int*)p;          p += (size_t)NB * 4;
    int* offs    = (int*)p;          p += (size_t)(NB + 1) * 4;
    int* cursor  = (int*)p;          p += (size_t)NB * 4;
    int* partial = (int*)p;          p += (size_t)NB * 4;
    int* blksum  = (int*)p;          p += (size_t)SCAN_BLK * 4;
    unsigned* keys = (unsigned*)p;   p += (size_t)NEDGES * 4;
    const size_t need_full = (size_t)(p - (char*)d_ws);

    if (ws_size >= need_full) {
        prep<<<PREP_ZBLK + 64, 256, 0, stream>>>(Z, W, Zh16, Wh16t, counts);
        gemm_f16<<<NMB * 4, 256, 0, stream>>>(Zh16, Wh16t, ZWh);
        hist_rows<<<(NEDGES + 255) / 256, 256, 0, stream>>>(EI, counts);
        scan_local<<<SCAN_BLK, 1024, 0, stream>>>(counts, partial, blksum);
        scan_fix<<<SCAN_BLK, 1024, 0, stream>>>(counts, partial, blksum, offs, cursor);
        scatter_edges<<<(NEDGES + 255) / 256, 256, 0, stream>>>(EI, cursor, keys);
        edge_score_q<<<NB / 4, 256, 0, stream>>>(ZWh, Zh16, keys, offs, out);
    } else {
        float* ZW = (float*)d_ws;
        dim3 g1((NNODES + GTM - 1) / GTM, DIM / GTN);
        gemm_zw<<<g1, 256, 0, stream>>>(Z, W, ZW);
        edge_score<<<NEDGES / 4, 256, 0, stream>>>(ZW, Z, EI, out);
    }
}

// Round 15
// 140.118 us; speedup vs baseline: 1.6745x; 1.0260x over previous
//
#include <hip/hip_runtime.h>
#include <math.h>

#define DIM     512
#define NNODES  10000
#define NEDGES  200000
#define MPAD    10048   // 157 * 64
#define NMB     157     // m-groups of 64
#define NGRP    5       // col groups of 2048 (c >> 11)
#define NB      (NGRP * NNODES)   // 50000 buckets
#define SCAN_BLK 49               // ceil(NB / 1024)

using short8  = __attribute__((ext_vector_type(8))) short;
using floatx4 = __attribute__((ext_vector_type(4))) float;
using half8   = __attribute__((ext_vector_type(8))) _Float16;
using half2v  = __attribute__((ext_vector_type(2))) _Float16;

__device__ inline float dot2acc(half2v a, half2v b, float c) {
#if __has_builtin(__builtin_amdgcn_fdot2)
    return __builtin_amdgcn_fdot2(a, b, c, false);
#else
    return fmaf((float)a[0], (float)b[0], fmaf((float)a[1], (float)b[1], c));
#endif
}

// ---------------------------------------------------------------------------
// prep: fused  (a) Z fp32 -> Zh16 fp16 [MPAD][512] (pad rows zeroed)
//              (b) W fp32 [k][n] -> Wh16t fp16 [n][k] (LDS tile transpose)
//              (c) zero bucket counts (50k)
// ---------------------------------------------------------------------------
#define PREP_ZBLK 2512
__global__ __launch_bounds__(256) void prep(const float* __restrict__ Z,
                                            const float* __restrict__ W,
                                            _Float16* __restrict__ Zh16,
                                            _Float16* __restrict__ Wh16t,
                                            int* __restrict__ counts) {
    const int b = blockIdx.x;
    const int t = threadIdx.x;

    if (b < 196) {                      // 196*256 = 50176 >= NB
        int i = b * 256 + t;
        if (i < NB) counts[i] = 0;
    }

    if (b < PREP_ZBLK) {
        const int idx8 = (b * 256 + t) * 8;
        const int m = idx8 >> 9;
        float x[8];
        if (m < NNODES) {
            float4 v0 = *(const float4*)(Z + idx8);
            float4 v1 = *(const float4*)(Z + idx8 + 4);
            x[0]=v0.x; x[1]=v0.y; x[2]=v0.z; x[3]=v0.w;
            x[4]=v1.x; x[5]=v1.y; x[6]=v1.z; x[7]=v1.w;
        } else {
            #pragma unroll
            for (int j = 0; j < 8; ++j) x[j] = 0.f;
        }
        half8 h;
        #pragma unroll
        for (int j = 0; j < 8; ++j) h[j] = (_Float16)x[j];
        *(half8*)(Zh16 + idx8) = h;
    } else {
        __shared__ float tile[64][65];
        const int wb = b - PREP_ZBLK;      // 0..63
        const int kb = (wb >> 3) * 64;
        const int nb = (wb & 7) * 64;
        const int kk = t >> 2;
        const int ch = t & 3;

        const float* src = W + (size_t)(kb + kk) * DIM + nb + ch * 16;
        #pragma unroll
        for (int q = 0; q < 4; ++q) {
            float4 v = *(const float4*)(src + q * 4);
            tile[kk][ch * 16 + q * 4 + 0] = v.x;
            tile[kk][ch * 16 + q * 4 + 1] = v.y;
            tile[kk][ch * 16 + q * 4 + 2] = v.z;
            tile[kk][ch * 16 + q * 4 + 3] = v.w;
        }
        __syncthreads();

        const int nn = kk;
        half8 h0, h1;
        #pragma unroll
        for (int i = 0; i < 8; ++i) h0[i] = (_Float16)tile[ch * 16 + i][nn];
        #pragma unroll
        for (int i = 0; i < 8; ++i) h1[i] = (_Float16)tile[ch * 16 + 8 + i][nn];
        _Float16* d = Wh16t + (size_t)(nb + nn) * DIM + kb + ch * 16;
        *(half8*)(d)     = h0;
        *(half8*)(d + 8) = h1;
    }
}

// ---------------------------------------------------------------------------
// GEMM: single-pass fp16 MFMA.  64m x 128n block, BK=32, 16 steps, grid 628.
// A/B via global_load_lds into double-buffered LDS, ONE barrier per step.
// ---------------------------------------------------------------------------
__global__ __launch_bounds__(256) void gemm_f16(const _Float16* __restrict__ Zh16,
                                                const _Float16* __restrict__ Wh16t,
                                                _Float16* __restrict__ ZWh) {
    __shared__ _Float16 Abuf[2][64 * 32];
    __shared__ _Float16 Bbuf[2][128 * 32];

    const int t     = threadIdx.x;
    const int bid   = blockIdx.x;
    const int n_idx = bid & 3;
    const int m0    = (bid >> 2) * 64;
    const int n0    = n_idx * 128;

    const int l  = t & 63;
    const int w  = t >> 6;
    const int wn = w * 32;
    const int lm = l & 15;
    const int lq = l >> 4;
    const unsigned wbase = (unsigned)(t & 192);

    floatx4 acc[4][2] = {};

    const int arow = t >> 2;
    const int ach  = t & 3;

    auto stage = [&](int buf, int k0) {
        {
            const _Float16* s = Zh16 + (size_t)(m0 + arow) * DIM + k0 + ach * 8;
            __builtin_amdgcn_global_load_lds(
                (const __attribute__((address_space(1))) void*)s,
                (__attribute__((address_space(3))) void*)&Abuf[buf][wbase * 8], 16, 0, 0);
        }
        #pragma unroll
        for (int p = 0; p < 2; ++p) {
            const int sidx = p * 256 + t;
            const int row  = sidx >> 2;
            const int ch   = sidx & 3;
            const _Float16* s = Wh16t + (size_t)(n0 + row) * DIM + k0 + ch * 8;
            __builtin_amdgcn_global_load_lds(
                (const __attribute__((address_space(1))) void*)s,
                (__attribute__((address_space(3))) void*)&Bbuf[buf][(p * 256 + wbase) * 8], 16, 0, 0);
        }
    };

    stage(0, 0);
    __syncthreads();

    for (int s = 0; s < 16; ++s) {
        const int buf = s & 1;
        if (s < 15) stage(buf ^ 1, (s + 1) * 32);

        half8 aF[4], bF[2];
        #pragma unroll
        for (int i = 0; i < 4; ++i)
            aF[i] = *(const half8*)&Abuf[buf][(16 * i + lm) * 32 + lq * 8];
        #pragma unroll
        for (int j = 0; j < 2; ++j)
            bF[j] = *(const half8*)&Bbuf[buf][(wn + 16 * j + lm) * 32 + lq * 8];

        #pragma unroll
        for (int i = 0; i < 4; ++i)
            #pragma unroll
            for (int j = 0; j < 2; ++j)
                acc[i][j] = __builtin_amdgcn_mfma_f32_16x16x32_f16(aF[i], bF[j], acc[i][j], 0, 0, 0);

        __syncthreads();
    }

    #pragma unroll
    for (int i = 0; i < 4; ++i)
        #pragma unroll
        for (int j = 0; j < 2; ++j)
            #pragma unroll
            for (int r = 0; r < 4; ++r) {
                const int gm = m0 + 16 * i + lq * 4 + r;
                const int gn = n0 + wn + 16 * j + lm;
                if (gm < NNODES)
                    ZWh[(size_t)gm * DIM + gn] = (_Float16)acc[i][j][r];
            }
}

// ---------------------------------------------------------------------------
// Counting sort by (col-group, row): bucket = (c>>11)*NNODES + r
// ---------------------------------------------------------------------------
__global__ void hist_rows(const int* __restrict__ eidx, int* __restrict__ counts) {
    int e = blockIdx.x * blockDim.x + threadIdx.x;
    if (e < NEDGES) {
        int r = eidx[e];
        int c = eidx[NEDGES + e];
        atomicAdd(&counts[(c >> 11) * NNODES + r], 1);
    }
}

// Phase 1: per-block exclusive scan (1024 contiguous counters per block).
__global__ __launch_bounds__(1024) void scan_local(const int* __restrict__ counts,
                                                   int* __restrict__ partial,
                                                   int* __restrict__ blksum) {
    __shared__ int wsum[16];
    __shared__ int woff[17];
    const int t    = threadIdx.x;
    const int lane = t & 63;
    const int wv   = t >> 6;
    const int i    = blockIdx.x * 1024 + t;

    int x = (i < NB) ? counts[i] : 0;

    int v = x;   // inclusive wave scan
    #pragma unroll
    for (int off = 1; off < 64; off <<= 1) {
        int u = __shfl_up(v, off, 64);
        if (lane >= off) v += u;
    }
    if (lane == 63) wsum[wv] = v;
    __syncthreads();
    if (t == 0) {
        int r = 0;
        #pragma unroll
        for (int k = 0; k < 16; ++k) { woff[k] = r; r += wsum[k]; }
        woff[16] = r;
    }
    __syncthreads();

    if (i < NB) partial[i] = woff[wv] + (v - x);   // block-local exclusive
    if (t == 1023) blksum[blockIdx.x] = woff[16];
}

// Phase 2: add block-base (wave-reduction over blksum) and emit cursor.
__global__ __launch_bounds__(1024) void scan_fix(const int* __restrict__ partial,
                                                 const int* __restrict__ blksum,
                                                 int* __restrict__ cursor) {
    __shared__ int base_s;
    const int t = threadIdx.x;
    const int b = blockIdx.x;

    if (t < 64) {
        int v = (t < b) ? blksum[t] : 0;     // SCAN_BLK=49 <= 64
        #pragma unroll
        for (int off = 32; off > 0; off >>= 1)
            v += __shfl_xor(v, off, 64);
        if (t == 0) base_s = v;
    }
    __syncthreads();
    const int base = base_s;

    const int i = b * 1024 + t;
    if (i < NB)
        cursor[i] = base + partial[i];
}

// scatter emits key (c<<18|e) AND row id (ushort) per slot.
__global__ void scatter_edges(const int* __restrict__ eidx,
                              int* __restrict__ cursor,
                              unsigned* __restrict__ keys,
                              unsigned short* __restrict__ rows16) {
    int e = blockIdx.x * blockDim.x + threadIdx.x;
    if (e < NEDGES) {
        int r = eidx[e];
        int c = eidx[NEDGES + e];
        int pos = atomicAdd(&cursor[(c >> 11) * NNODES + r], 1);
        keys[pos]   = ((unsigned)c << 18) | (unsigned)e;
        rows16[pos] = (unsigned short)r;
    }
}

// ---------------------------------------------------------------------------
// Edge scoring v6 (flat): wave w handles edges 4w..4w+3 of the sorted array.
// 16 lanes/edge; per lane 4 row-frag + 4 col-frag b128 loads, all independent
// (8 in flight). Perfect load balance; L2 slice locality from the sort order.
// Grid: 12500 blocks x 256 (NEDGES = 12500*16 exactly).
// ---------------------------------------------------------------------------
__global__ __launch_bounds__(256) void edge_score_f(const _Float16* __restrict__ ZWh,
                                                    const _Float16* __restrict__ Zh,
                                                    const unsigned* __restrict__ keys,
                                                    const unsigned short* __restrict__ rows16,
                                                    float* __restrict__ out) {
    const int t    = threadIdx.x;
    const int wgid = blockIdx.x * 4 + (t >> 6);   // global wave id
    const int lane = t & 63;
    const int gq   = lane >> 4;                   // edge slot 0..3
    const int sl   = lane & 15;                   // sub-lane

    const int ii = wgid * 4 + gq;                 // < NEDGES by construction
    const unsigned k = keys[ii];
    const int c = (int)(k >> 18);
    const int r = (int)rows16[ii];

    const _Float16* rp = ZWh + (size_t)r * DIM + sl * 32;
    const _Float16* cp = Zh  + (size_t)c * DIM + sl * 32;

    half8 ra0 = *(const half8*)(rp);
    half8 ra1 = *(const half8*)(rp + 8);
    half8 ra2 = *(const half8*)(rp + 16);
    half8 ra3 = *(const half8*)(rp + 24);
    half8 c0  = *(const half8*)(cp);
    half8 c1  = *(const half8*)(cp + 8);
    half8 c2  = *(const half8*)(cp + 16);
    half8 c3  = *(const half8*)(cp + 24);

    float s = 0.f;
    #pragma unroll
    for (int d = 0; d < 4; ++d) {
        s = dot2acc((half2v){ra0[2*d], ra0[2*d+1]}, (half2v){c0[2*d], c0[2*d+1]}, s);
        s = dot2acc((half2v){ra1[2*d], ra1[2*d+1]}, (half2v){c1[2*d], c1[2*d+1]}, s);
        s = dot2acc((half2v){ra2[2*d], ra2[2*d+1]}, (half2v){c2[2*d], c2[2*d+1]}, s);
        s = dot2acc((half2v){ra3[2*d], ra3[2*d+1]}, (half2v){c3[2*d], c3[2*d+1]}, s);
    }

    // reduce within each 16-lane group (4 edges simultaneously)
    s += __shfl_xor(s, 1, 64);
    s += __shfl_xor(s, 2, 64);
    s += __shfl_xor(s, 4, 64);
    s += __shfl_xor(s, 8, 64);

    if (sl == 0)
        out[k & 0x3FFFFu] = 1.0f / (1.0f + expf(-s));
}

// ---------------------------------------------------------------------------
// fp32 fallback path (ws too small)
// ---------------------------------------------------------------------------
#define GTM 128
#define GTN 64
#define GTK 16
#define LDA 132
#define LDB 68

__global__ __launch_bounds__(256) void gemm_zw(const float* __restrict__ A,
                                               const float* __restrict__ B,
                                               float* __restrict__ C) {
    __shared__ float As[GTK * LDA];
    __shared__ float Bs[GTK * LDB];

    const int t  = threadIdx.x;
    const int m0 = blockIdx.x * GTM;
    const int n0 = blockIdx.y * GTN;
    const int tx = t & 15;
    const int ty = t >> 4;

    float acc[8][4] = {};

    for (int k0 = 0; k0 < DIM; k0 += GTK) {
        #pragma unroll
        for (int p = 0; p < 2; ++p) {
            int f  = t + p * 256;
            int mm = f >> 2;
            int kq = f & 3;
            int m  = m0 + mm;
            float4 v = make_float4(0.f, 0.f, 0.f, 0.f);
            if (m < NNODES)
                v = *(const float4*)(A + (size_t)m * DIM + k0 + kq * 4);
            As[(kq * 4 + 0) * LDA + mm] = v.x;
            As[(kq * 4 + 1) * LDA + mm] = v.y;
            As[(kq * 4 + 2) * LDA + mm] = v.z;
            As[(kq * 4 + 3) * LDA + mm] = v.w;
        }
        {
            int kb = t >> 4, n4 = t & 15;
            *(float4*)&Bs[kb * LDB + n4 * 4] =
                *(const float4*)(B + (size_t)(k0 + kb) * DIM + n0 + n4 * 4);
        }
        __syncthreads();

        #pragma unroll
        for (int kk = 0; kk < GTK; ++kk) {
            float4 a0 = *(const float4*)&As[kk * LDA + ty * 8];
            float4 a1 = *(const float4*)&As[kk * LDA + ty * 8 + 4];
            float4 b  = *(const float4*)&Bs[kk * LDB + tx * 4];
            float av[8] = {a0.x, a0.y, a0.z, a0.w, a1.x, a1.y, a1.z, a1.w};
            float bv[4] = {b.x, b.y, b.z, b.w};
            #pragma unroll
            for (int i = 0; i < 8; ++i)
                #pragma unroll
                for (int j = 0; j < 4; ++j)
                    acc[i][j] = fmaf(av[i], bv[j], acc[i][j]);
        }
        __syncthreads();
    }

    #pragma unroll
    for (int i = 0; i < 8; ++i) {
        int m = m0 + ty * 8 + i;
        if (m < NNODES)
            *(float4*)(C + (size_t)m * DIM + n0 + tx * 4) =
                make_float4(acc[i][0], acc[i][1], acc[i][2], acc[i][3]);
    }
}

__global__ __launch_bounds__(256) void edge_score(const float* __restrict__ ZW,
                                                  const float* __restrict__ Z,
                                                  const int* __restrict__ eidx,
                                                  float* __restrict__ out) {
    const int e    = blockIdx.x * 4 + (threadIdx.x >> 6);
    const int lane = threadIdx.x & 63;

    const int r = eidx[e];
    const int c = eidx[NEDGES + e];

    const float4* pr = (const float4*)(ZW + (size_t)r * DIM);
    const float4* pc = (const float4*)(Z  + (size_t)c * DIM);

    float4 a0 = pr[lane * 2 + 0];
    float4 a1 = pr[lane * 2 + 1];
    float4 b0 = pc[lane * 2 + 0];
    float4 b1 = pc[lane * 2 + 1];

    float s = a0.x * b0.x;
    s = fmaf(a0.y, b0.y, s);
    s = fmaf(a0.z, b0.z, s);
    s = fmaf(a0.w, b0.w, s);
    s = fmaf(a1.x, b1.x, s);
    s = fmaf(a1.y, b1.y, s);
    s = fmaf(a1.z, b1.z, s);
    s = fmaf(a1.w, b1.w, s);

    #pragma unroll
    for (int off = 32; off > 0; off >>= 1)
        s += __shfl_xor(s, off, 64);

    if (lane == 0)
        out[e] = 1.0f / (1.0f + expf(-s));
}

// ---------------------------------------------------------------------------
extern "C" void kernel_launch(void* const* d_in, const int* in_sizes, int n_in,
                              void* d_out, int out_size, void* d_ws, size_t ws_size,
                              hipStream_t stream) {
    const float* Z  = (const float*)d_in[0];
    const float* W  = (const float*)d_in[1];
    const int*   EI = (const int*)d_in[2];
    float* out = (float*)d_out;

    char* p = (char*)d_ws;
    _Float16* ZWh   = (_Float16*)p;  p += (size_t)MPAD * DIM * 2;
    _Float16* Zh16  = (_Float16*)p;  p += (size_t)MPAD * DIM * 2;
    _Float16* Wh16t = (_Float16*)p;  p += (size_t)DIM * DIM * 2;
    int* counts  = (int*)p;          p += (size_t)NB * 4;
    int* cursor  = (int*)p;          p += (size_t)NB * 4;
    int* partial = (int*)p;          p += (size_t)NB * 4;
    int* blksum  = (int*)p;          p += (size_t)SCAN_BLK * 4;
    unsigned* keys = (unsigned*)p;   p += (size_t)NEDGES * 4;
    unsigned short* rows16 = (unsigned short*)p; p += (size_t)NEDGES * 2;
    const size_t need_full = (size_t)(p - (char*)d_ws);

    if (ws_size >= need_full) {
        prep<<<PREP_ZBLK + 64, 256, 0, stream>>>(Z, W, Zh16, Wh16t, counts);
        gemm_f16<<<NMB * 4, 256, 0, stream>>>(Zh16, Wh16t, ZWh);
        hist_rows<<<(NEDGES + 255) / 256, 256, 0, stream>>>(EI, counts);
        scan_local<<<SCAN_BLK, 1024, 0, stream>>>(counts, partial, blksum);
        scan_fix<<<SCAN_BLK, 1024, 0, stream>>>(partial, blksum, cursor);
        scatter_edges<<<(NEDGES + 255) / 256, 256, 0, stream>>>(EI, cursor, keys, rows16);
        edge_score_f<<<NEDGES / 16, 256, 0, stream>>>(ZWh, Zh16, keys, rows16, out);
    } else {
        float* ZW = (float*)d_ws;
        dim3 g1((NNODES + GTM - 1) / GTM, DIM / GTN);
        gemm_zw<<<g1, 256, 0, stream>>>(Z, W, ZW);
        edge_score<<<NEDGES / 4, 256, 0, stream>>>(ZW, Z, EI, out);
    }
}

// Round 16
// 135.795 us; speedup vs baseline: 1.7279x; 1.0318x over previous
//
#include <hip/hip_runtime.h>
#include <math.h>

#define DIM     512
#define NNODES  10000
#define NEDGES  200000
#define MPAD    10048   // 157 * 64
#define NMB     157     // m-groups of 64
#define NGRP    5       // col groups of 2048 (c >> 11)
#define NB      (NGRP * NNODES)   // 50000 buckets
#define SCAN_BLK 49               // ceil(NB / 1024)
#define GEMM_GRID (NMB * 4)       // 628

using short8  = __attribute__((ext_vector_type(8))) short;
using floatx4 = __attribute__((ext_vector_type(4))) float;
using half8   = __attribute__((ext_vector_type(8))) _Float16;
using half2v  = __attribute__((ext_vector_type(2))) _Float16;

__device__ inline float dot2acc(half2v a, half2v b, float c) {
#if __has_builtin(__builtin_amdgcn_fdot2)
    return __builtin_amdgcn_fdot2(a, b, c, false);
#else
    return fmaf((float)a[0], (float)b[0], fmaf((float)a[1], (float)b[1], c));
#endif
}

// ---------------------------------------------------------------------------
// prep: fused  (a) Z fp32 -> Zh16 fp16 [MPAD][512] (pad rows zeroed)
//              (b) W fp32 [k][n] -> Wh16t fp16 [n][k] (LDS tile transpose)
//              (c) zero bucket counts (50k)
// ---------------------------------------------------------------------------
#define PREP_ZBLK 2512
__global__ __launch_bounds__(256) void prep(const float* __restrict__ Z,
                                            const float* __restrict__ W,
                                            _Float16* __restrict__ Zh16,
                                            _Float16* __restrict__ Wh16t,
                                            int* __restrict__ counts) {
    const int b = blockIdx.x;
    const int t = threadIdx.x;

    if (b < 196) {                      // 196*256 = 50176 >= NB
        int i = b * 256 + t;
        if (i < NB) counts[i] = 0;
    }

    if (b < PREP_ZBLK) {
        const int idx8 = (b * 256 + t) * 8;
        const int m = idx8 >> 9;
        float x[8];
        if (m < NNODES) {
            float4 v0 = *(const float4*)(Z + idx8);
            float4 v1 = *(const float4*)(Z + idx8 + 4);
            x[0]=v0.x; x[1]=v0.y; x[2]=v0.z; x[3]=v0.w;
            x[4]=v1.x; x[5]=v1.y; x[6]=v1.z; x[7]=v1.w;
        } else {
            #pragma unroll
            for (int j = 0; j < 8; ++j) x[j] = 0.f;
        }
        half8 h;
        #pragma unroll
        for (int j = 0; j < 8; ++j) h[j] = (_Float16)x[j];
        *(half8*)(Zh16 + idx8) = h;
    } else {
        __shared__ float tile[64][65];
        const int wb = b - PREP_ZBLK;      // 0..63
        const int kb = (wb >> 3) * 64;
        const int nb = (wb & 7) * 64;
        const int kk = t >> 2;
        const int ch = t & 3;

        const float* src = W + (size_t)(kb + kk) * DIM + nb + ch * 16;
        #pragma unroll
        for (int q = 0; q < 4; ++q) {
            float4 v = *(const float4*)(src + q * 4);
            tile[kk][ch * 16 + q * 4 + 0] = v.x;
            tile[kk][ch * 16 + q * 4 + 1] = v.y;
            tile[kk][ch * 16 + q * 4 + 2] = v.z;
            tile[kk][ch * 16 + q * 4 + 3] = v.w;
        }
        __syncthreads();

        const int nn = kk;
        half8 h0, h1;
        #pragma unroll
        for (int i = 0; i < 8; ++i) h0[i] = (_Float16)tile[ch * 16 + i][nn];
        #pragma unroll
        for (int i = 0; i < 8; ++i) h1[i] = (_Float16)tile[ch * 16 + 8 + i][nn];
        _Float16* d = Wh16t + (size_t)(nb + nn) * DIM + kb + ch * 16;
        *(half8*)(d)     = h0;
        *(half8*)(d + 8) = h1;
    }
}

// ---------------------------------------------------------------------------
// GEMM v8: single-pass fp16 MFMA. 64m x 128n block, BK=64, 8 steps, grid 628.
// LDS layout [buf][kk][row][32 halves] (validated 64B rows); dbuf 48 KB ->
// 3 blocks/CU; ONE barrier per step, prefetch flies over 16 MFMA.
// Epilogue: grid-stride histogram of edge buckets (counts zeroed by prep,
// ordering guaranteed by stream order).
// ---------------------------------------------------------------------------
__global__ __launch_bounds__(256) void gemm_f16(const _Float16* __restrict__ Zh16,
                                                const _Float16* __restrict__ Wh16t,
                                                _Float16* __restrict__ ZWh,
                                                const int* __restrict__ eidx,
                                                int* __restrict__ counts) {
    __shared__ _Float16 Abuf[2][2 * 64 * 32];    // [buf][kk*2048 + row*32]
    __shared__ _Float16 Bbuf[2][2 * 128 * 32];   // [buf][kk*4096 + row*32]

    const int t     = threadIdx.x;
    const int bid   = blockIdx.x;
    const int n_idx = bid & 3;
    const int m0    = (bid >> 2) * 64;
    const int n0    = n_idx * 128;

    const int l  = t & 63;
    const int w  = t >> 6;
    const int wn = w * 32;
    const int lm = l & 15;
    const int lq = l >> 4;
    const unsigned wbase = (unsigned)(t & 192);

    floatx4 acc[4][2] = {};

    auto stage = [&](int buf, int k0) {
        // A: 64 rows x 64 halves = 2 kk-subtiles x 256 slots of 16B (2/thread)
        #pragma unroll
        for (int p = 0; p < 2; ++p) {
            const int s   = p * 256 + t;
            const int kk  = s >> 8;
            const int row = (s >> 2) & 63;
            const int ch  = s & 3;
            const _Float16* src = Zh16 + (size_t)(m0 + row) * DIM + k0 + kk * 32 + ch * 8;
            __builtin_amdgcn_global_load_lds(
                (const __attribute__((address_space(1))) void*)src,
                (__attribute__((address_space(3))) void*)&Abuf[buf][(p * 256 + wbase) * 8],
                16, 0, 0);
        }
        // B: 128 rows x 64 halves = 2 kk-subtiles x 512 slots of 16B (4/thread)
        #pragma unroll
        for (int p = 0; p < 4; ++p) {
            const int s   = p * 256 + t;
            const int kk  = s >> 9;
            const int row = (s >> 2) & 127;
            const int ch  = s & 3;
            const _Float16* src = Wh16t + (size_t)(n0 + row) * DIM + k0 + kk * 32 + ch * 8;
            __builtin_amdgcn_global_load_lds(
                (const __attribute__((address_space(1))) void*)src,
                (__attribute__((address_space(3))) void*)&Bbuf[buf][(p * 256 + wbase) * 8],
                16, 0, 0);
        }
    };

    stage(0, 0);
    __syncthreads();

    for (int s = 0; s < 8; ++s) {
        const int buf = s & 1;
        if (s < 7) stage(buf ^ 1, (s + 1) * 64);   // flies across 16 MFMA

        #pragma unroll
        for (int kk = 0; kk < 2; ++kk) {
            half8 aF[4], bF[2];
            #pragma unroll
            for (int i = 0; i < 4; ++i)
                aF[i] = *(const half8*)&Abuf[buf][kk * 2048 + (16 * i + lm) * 32 + lq * 8];
            #pragma unroll
            for (int j = 0; j < 2; ++j)
                bF[j] = *(const half8*)&Bbuf[buf][kk * 4096 + (wn + 16 * j + lm) * 32 + lq * 8];

            #pragma unroll
            for (int i = 0; i < 4; ++i)
                #pragma unroll
                for (int j = 0; j < 2; ++j)
                    acc[i][j] = __builtin_amdgcn_mfma_f32_16x16x32_f16(aF[i], bF[j], acc[i][j], 0, 0, 0);
        }

        __syncthreads();   // single barrier: drains prefetch (overlapped), WAR-safe
    }

    #pragma unroll
    for (int i = 0; i < 4; ++i)
        #pragma unroll
        for (int j = 0; j < 2; ++j)
            #pragma unroll
            for (int r = 0; r < 4; ++r) {
                const int gm = m0 + 16 * i + lq * 4 + r;
                const int gn = n0 + wn + 16 * j + lm;
                if (gm < NNODES)
                    ZWh[(size_t)gm * DIM + gn] = (_Float16)acc[i][j][r];
            }

    // fused histogram (counts pre-zeroed by prep; stream order guarantees it)
    for (int e = bid * 256 + t; e < NEDGES; e += GEMM_GRID * 256) {
        int r = eidx[e];
        int c = eidx[NEDGES + e];
        atomicAdd(&counts[(c >> 11) * NNODES + r], 1);
    }
}

// ---------------------------------------------------------------------------
// Scan phase 1: per-block exclusive scan (1024 contiguous counters / block).
// ---------------------------------------------------------------------------
__global__ __launch_bounds__(1024) void scan_local(const int* __restrict__ counts,
                                                   int* __restrict__ partial,
                                                   int* __restrict__ blksum) {
    __shared__ int wsum[16];
    __shared__ int woff[17];
    const int t    = threadIdx.x;
    const int lane = t & 63;
    const int wv   = t >> 6;
    const int i    = blockIdx.x * 1024 + t;

    int x = (i < NB) ? counts[i] : 0;

    int v = x;   // inclusive wave scan
    #pragma unroll
    for (int off = 1; off < 64; off <<= 1) {
        int u = __shfl_up(v, off, 64);
        if (lane >= off) v += u;
    }
    if (lane == 63) wsum[wv] = v;
    __syncthreads();
    if (t == 0) {
        int r = 0;
        #pragma unroll
        for (int k = 0; k < 16; ++k) { woff[k] = r; r += wsum[k]; }
        woff[16] = r;
    }
    __syncthreads();

    if (i < NB) partial[i] = woff[wv] + (v - x);
    if (t == 1023) blksum[blockIdx.x] = woff[16];
}

// Scan phase 2: add block base, emit cursor.
__global__ __launch_bounds__(1024) void scan_fix(const int* __restrict__ partial,
                                                 const int* __restrict__ blksum,
                                                 int* __restrict__ cursor) {
    __shared__ int base_s;
    const int t = threadIdx.x;
    const int b = blockIdx.x;

    if (t < 64) {
        int v = (t < b) ? blksum[t] : 0;     // SCAN_BLK=49 <= 64
        #pragma unroll
        for (int off = 32; off > 0; off >>= 1)
            v += __shfl_xor(v, off, 64);
        if (t == 0) base_s = v;
    }
    __syncthreads();
    const int base = base_s;

    const int i = b * 1024 + t;
    if (i < NB)
        cursor[i] = base + partial[i];
}

// scatter emits key (c<<18|e) AND row id (ushort) per slot.
__global__ void scatter_edges(const int* __restrict__ eidx,
                              int* __restrict__ cursor,
                              unsigned* __restrict__ keys,
                              unsigned short* __restrict__ rows16) {
    int e = blockIdx.x * blockDim.x + threadIdx.x;
    if (e < NEDGES) {
        int r = eidx[e];
        int c = eidx[NEDGES + e];
        int pos = atomicAdd(&cursor[(c >> 11) * NNODES + r], 1);
        keys[pos]   = ((unsigned)c << 18) | (unsigned)e;
        rows16[pos] = (unsigned short)r;
    }
}

// ---------------------------------------------------------------------------
// Edge scoring (flat): wave w handles edges 4w..4w+3 of the sorted array.
// 16 lanes/edge; 8 independent b128 loads per lane; perfect load balance.
// ---------------------------------------------------------------------------
__global__ __launch_bounds__(256) void edge_score_f(const _Float16* __restrict__ ZWh,
                                                    const _Float16* __restrict__ Zh,
                                                    const unsigned* __restrict__ keys,
                                                    const unsigned short* __restrict__ rows16,
                                                    float* __restrict__ out) {
    const int t    = threadIdx.x;
    const int wgid = blockIdx.x * 4 + (t >> 6);
    const int lane = t & 63;
    const int gq   = lane >> 4;
    const int sl   = lane & 15;

    const int ii = wgid * 4 + gq;
    const unsigned k = keys[ii];
    const int c = (int)(k >> 18);
    const int r = (int)rows16[ii];

    const _Float16* rp = ZWh + (size_t)r * DIM + sl * 32;
    const _Float16* cp = Zh  + (size_t)c * DIM + sl * 32;

    half8 ra0 = *(const half8*)(rp);
    half8 ra1 = *(const half8*)(rp + 8);
    half8 ra2 = *(const half8*)(rp + 16);
    half8 ra3 = *(const half8*)(rp + 24);
    half8 c0  = *(const half8*)(cp);
    half8 c1  = *(const half8*)(cp + 8);
    half8 c2  = *(const half8*)(cp + 16);
    half8 c3  = *(const half8*)(cp + 24);

    float s = 0.f;
    #pragma unroll
    for (int d = 0; d < 4; ++d) {
        s = dot2acc((half2v){ra0[2*d], ra0[2*d+1]}, (half2v){c0[2*d], c0[2*d+1]}, s);
        s = dot2acc((half2v){ra1[2*d], ra1[2*d+1]}, (half2v){c1[2*d], c1[2*d+1]}, s);
        s = dot2acc((half2v){ra2[2*d], ra2[2*d+1]}, (half2v){c2[2*d], c2[2*d+1]}, s);
        s = dot2acc((half2v){ra3[2*d], ra3[2*d+1]}, (half2v){c3[2*d], c3[2*d+1]}, s);
    }

    s += __shfl_xor(s, 1, 64);
    s += __shfl_xor(s, 2, 64);
    s += __shfl_xor(s, 4, 64);
    s += __shfl_xor(s, 8, 64);

    if (sl == 0)
        out[k & 0x3FFFFu] = 1.0f / (1.0f + expf(-s));
}

// ---------------------------------------------------------------------------
// fp32 fallback path (ws too small)
// ---------------------------------------------------------------------------
#define GTM 128
#define GTN 64
#define GTK 16
#define LDA 132
#define LDB 68

__global__ __launch_bounds__(256) void gemm_zw(const float* __restrict__ A,
                                               const float* __restrict__ B,
                                               float* __restrict__ C) {
    __shared__ float As[GTK * LDA];
    __shared__ float Bs[GTK * LDB];

    const int t  = threadIdx.x;
    const int m0 = blockIdx.x * GTM;
    const int n0 = blockIdx.y * GTN;
    const int tx = t & 15;
    const int ty = t >> 4;

    float acc[8][4] = {};

    for (int k0 = 0; k0 < DIM; k0 += GTK) {
        #pragma unroll
        for (int p = 0; p < 2; ++p) {
            int f  = t + p * 256;
            int mm = f >> 2;
            int kq = f & 3;
            int m  = m0 + mm;
            float4 v = make_float4(0.f, 0.f, 0.f, 0.f);
            if (m < NNODES)
                v = *(const float4*)(A + (size_t)m * DIM + k0 + kq * 4);
            As[(kq * 4 + 0) * LDA + mm] = v.x;
            As[(kq * 4 + 1) * LDA + mm] = v.y;
            As[(kq * 4 + 2) * LDA + mm] = v.z;
            As[(kq * 4 + 3) * LDA + mm] = v.w;
        }
        {
            int kb = t >> 4, n4 = t & 15;
            *(float4*)&Bs[kb * LDB + n4 * 4] =
                *(const float4*)(B + (size_t)(k0 + kb) * DIM + n0 + n4 * 4);
        }
        __syncthreads();

        #pragma unroll
        for (int kk = 0; kk < GTK; ++kk) {
            float4 a0 = *(const float4*)&As[kk * LDA + ty * 8];
            float4 a1 = *(const float4*)&As[kk * LDA + ty * 8 + 4];
            float4 b  = *(const float4*)&Bs[kk * LDB + tx * 4];
            float av[8] = {a0.x, a0.y, a0.z, a0.w, a1.x, a1.y, a1.z, a1.w};
            float bv[4] = {b.x, b.y, b.z, b.w};
            #pragma unroll
            for (int i = 0; i < 8; ++i)
                #pragma unroll
                for (int j = 0; j < 4; ++j)
                    acc[i][j] = fmaf(av[i], bv[j], acc[i][j]);
        }
        __syncthreads();
    }

    #pragma unroll
    for (int i = 0; i < 8; ++i) {
        int m = m0 + ty * 8 + i;
        if (m < NNODES)
            *(float4*)(C + (size_t)m * DIM + n0 + tx * 4) =
                make_float4(acc[i][0], acc[i][1], acc[i][2], acc[i][3]);
    }
}

__global__ __launch_bounds__(256) void edge_score(const float* __restrict__ ZW,
                                                  const float* __restrict__ Z,
                                                  const int* __restrict__ eidx,
                                                  float* __restrict__ out) {
    const int e    = blockIdx.x * 4 + (threadIdx.x >> 6);
    const int lane = threadIdx.x & 63;

    const int r = eidx[e];
    const int c = eidx[NEDGES + e];

    const float4* pr = (const float4*)(ZW + (size_t)r * DIM);
    const float4* pc = (const float4*)(Z  + (size_t)c * DIM);

    float4 a0 = pr[lane * 2 + 0];
    float4 a1 = pr[lane * 2 + 1];
    float4 b0 = pc[lane * 2 + 0];
    float4 b1 = pc[lane * 2 + 1];

    float s = a0.x * b0.x;
    s = fmaf(a0.y, b0.y, s);
    s = fmaf(a0.z, b0.z, s);
    s = fmaf(a0.w, b0.w, s);
    s = fmaf(a1.x, b1.x, s);
    s = fmaf(a1.y, b1.y, s);
    s = fmaf(a1.z, b1.z, s);
    s = fmaf(a1.w, b1.w, s);

    #pragma unroll
    for (int off = 32; off > 0; off >>= 1)
        s += __shfl_xor(s, off, 64);

    if (lane == 0)
        out[e] = 1.0f / (1.0f + expf(-s));
}

// ---------------------------------------------------------------------------
extern "C" void kernel_launch(void* const* d_in, const int* in_sizes, int n_in,
                              void* d_out, int out_size, void* d_ws, size_t ws_size,
                              hipStream_t stream) {
    const float* Z  = (const float*)d_in[0];
    const float* W  = (const float*)d_in[1];
    const int*   EI = (const int*)d_in[2];
    float* out = (float*)d_out;

    char* p = (char*)d_ws;
    _Float16* ZWh   = (_Float16*)p;  p += (size_t)MPAD * DIM * 2;
    _Float16* Zh16  = (_Float16*)p;  p += (size_t)MPAD * DIM * 2;
    _Float16* Wh16t = (_Float16*)p;  p += (size_t)DIM * DIM * 2;
    int* counts  = (int*)p;          p += (size_t)NB * 4;
    int* cursor  = (int*)p;          p += (size_t)NB * 4;
    int* partial = (int*)p;          p += (size_t)NB * 4;
    int* blksum  = (int*)p;          p += (size_t)SCAN_BLK * 4;
    unsigned* keys = (unsigned*)p;   p += (size_t)NEDGES * 4;
    unsigned short* rows16 = (unsigned short*)p; p += (size_t)NEDGES * 2;
    const size_t need_full = (size_t)(p - (char*)d_ws);

    if (ws_size >= need_full) {
        prep<<<PREP_ZBLK + 64, 256, 0, stream>>>(Z, W, Zh16, Wh16t, counts);
        gemm_f16<<<GEMM_GRID, 256, 0, stream>>>(Zh16, Wh16t, ZWh, EI, counts);
        scan_local<<<SCAN_BLK, 1024, 0, stream>>>(counts, partial, blksum);
        scan_fix<<<SCAN_BLK, 1024, 0, stream>>>(partial, blksum, cursor);
        scatter_edges<<<(NEDGES + 255) / 256, 256, 0, stream>>>(EI, cursor, keys, rows16);
        edge_score_f<<<NEDGES / 16, 256, 0, stream>>>(ZWh, Zh16, keys, rows16, out);
    } else {
        float* ZW = (float*)d_ws;
        dim3 g1((NNODES + GTM - 1) / GTM, DIM / GTN);
        gemm_zw<<<g1, 256, 0, stream>>>(Z, W, ZW);
        edge_score<<<NEDGES / 4, 256, 0, stream>>>(ZW, Z, EI, out);
    }
}